// Round 9
// baseline (169.371 us; speedup 1.0000x reference)
//
#include <hip/hip_runtime.h>
#include <math.h>

// YOLO-style loss: single fused kernel. R8's proven streaming body (2 cells/thread,
// 512-cell chunks). Finalize fused WITHOUT global atomics: per-block done-flags
// (distinct addresses, release stores) + block 0 spin-waits then reduces partials
// in fixed order (deterministic). R5/R6's regression was the single-address ticket
// atomicAdd (5408 serialized far-atomics), not fusion itself.

#define EPSV 1e-6f

#define CELL_BODY(pA, p4, pB, tA, t4, tB)                                         \
    {                                                                             \
        float m = ((t4) > 0.f) ? 1.f : 0.f;                                       \
        float px = 1.f / (1.f + __expf(-(pA).x));                                 \
        float py = 1.f / (1.f + __expf(-(pA).y));                                 \
        float dx = px - (tA).x;                                                   \
        float dy = py - (tA).y;                                                   \
        float dw = sqrtf(fabsf((pA).z) + EPSV) - sqrtf(fabsf((tA).z) + EPSV);     \
        float dh = sqrtf(fabsf((pA).w) + EPSV) - sqrtf(fabsf((tA).w) + EPSV);     \
        float coord = dx*dx + dy*dy + dw*dw + dh*dh;                              \
        float l1p4 = __logf(1.f + __expf(-fabsf(p4)));                            \
        float logsig_p4 = fminf((p4), 0.f) - l1p4;                                \
        float logsig_m4 = fminf(-(p4), 0.f) - l1p4;                               \
        float bce_obj = -((t4) * logsig_p4 + (1.f - (t4)) * logsig_m4);           \
        float bce_no4 = -logsig_m4;                                               \
        float bce_no9 = fmaxf((pB).x, 0.f) + __logf(1.f + __expf(-fabsf((pB).x)));\
        float t10 = (tB).y, t11 = (tB).z, t12 = (tB).w;                           \
        float p10 = (pB).y, p11 = (pB).z, p12 = (pB).w;                           \
        int tcls = 0; float bt = t10;                                             \
        if (t11 > bt) { bt = t11; tcls = 1; }                                     \
        if (t12 > bt) { tcls = 2; }                                               \
        float lt = (tcls == 0) ? p10 : ((tcls == 1) ? p11 : p12);                 \
        float mx = fmaxf(p10, fmaxf(p11, p12));                                   \
        float lse = mx + __logf(__expf(p10-mx) + __expf(p11-mx) + __expf(p12-mx));\
        float ce = lse - lt;                                                      \
        accA += m * (5.f * coord + bce_obj + ce);                                 \
        accB += (1.f - m) * (bce_no4 + bce_no9);                                  \
        accC += m;                                                                \
    }

typedef float f4u __attribute__((ext_vector_type(4), aligned(4)));

__global__ __launch_bounds__(256, 4) void phobia_fused(
    const float* __restrict__ pred, const float* __restrict__ tgt,
    int* __restrict__ flags, float* __restrict__ part,
    float* __restrict__ out, int nchunks, long long cells)
{
    float accA = 0.f, accB = 0.f, accC = 0.f;

    for (int c = blockIdx.x; c < nchunks; c += gridDim.x) {
        long long i0 = (long long)c * 512 + threadIdx.x;
        long long i1 = i0 + 256;

        const float* pr0 = pred + i0 * 16;
        const float* tr0 = tgt  + i0 * 13;
        const float* pr1 = pred + i1 * 16;
        const float* tr1 = tgt  + i1 * 13;

        f4u   pA0 = *reinterpret_cast<const f4u*>(pr0);
        float p40 = pr0[4];
        f4u   pB0 = *reinterpret_cast<const f4u*>(pr0 + 9);
        f4u   tA0 = *reinterpret_cast<const f4u*>(tr0);
        float t40 = tr0[4];
        f4u   tB0 = *reinterpret_cast<const f4u*>(tr0 + 9);

        f4u   pA1 = *reinterpret_cast<const f4u*>(pr1);
        float p41 = pr1[4];
        f4u   pB1 = *reinterpret_cast<const f4u*>(pr1 + 9);
        f4u   tA1 = *reinterpret_cast<const f4u*>(tr1);
        float t41 = tr1[4];
        f4u   tB1 = *reinterpret_cast<const f4u*>(tr1 + 9);

        CELL_BODY(pA0, p40, pB0, tA0, t40, tB0);
        CELL_BODY(pA1, p41, pB1, tA1, t41, tB1);
    }

    // block-level reduce
    #pragma unroll
    for (int o = 32; o > 0; o >>= 1) {
        accA += __shfl_down(accA, o, 64);
        accB += __shfl_down(accB, o, 64);
        accC += __shfl_down(accC, o, 64);
    }
    __shared__ float sA[4], sB[4], sC[4];
    int wave = threadIdx.x >> 6;
    int lane = threadIdx.x & 63;
    if (lane == 0) { sA[wave] = accA; sB[wave] = accB; sC[wave] = accC; }
    __syncthreads();
    if (threadIdx.x == 0) {
        part[blockIdx.x * 3 + 0] = sA[0] + sA[1] + sA[2] + sA[3];
        part[blockIdx.x * 3 + 1] = sB[0] + sB[1] + sB[2] + sB[3];
        part[blockIdx.x * 3 + 2] = sC[0] + sC[1] + sC[2] + sC[3];
        __threadfence();   // partials visible at device scope before flag
        __hip_atomic_store(&flags[blockIdx.x], 1, __ATOMIC_RELEASE, __HIP_MEMORY_SCOPE_AGENT);
    }

    if (blockIdx.x == 0) {
        // spin until every block has published (distinct addresses, no contention)
        int nb = gridDim.x;
        for (int k = threadIdx.x; k < nb; k += 256) {
            while (__hip_atomic_load(&flags[k], __ATOMIC_RELAXED, __HIP_MEMORY_SCOPE_AGENT) == 0) {
                __builtin_amdgcn_s_sleep(16);
            }
        }
        __syncthreads();
        __threadfence();   // acquire: partials ordered after observed flags

        float a = 0.f, b = 0.f, c = 0.f;
        for (int k = threadIdx.x; k < nb; k += 256) {
            a += __hip_atomic_load(&part[k * 3 + 0], __ATOMIC_RELAXED, __HIP_MEMORY_SCOPE_AGENT);
            b += __hip_atomic_load(&part[k * 3 + 1], __ATOMIC_RELAXED, __HIP_MEMORY_SCOPE_AGENT);
            c += __hip_atomic_load(&part[k * 3 + 2], __ATOMIC_RELAXED, __HIP_MEMORY_SCOPE_AGENT);
        }
        #pragma unroll
        for (int o = 32; o > 0; o >>= 1) {
            a += __shfl_down(a, o, 64);
            b += __shfl_down(b, o, 64);
            c += __shfl_down(c, o, 64);
        }
        if (lane == 0) { sA[wave] = a; sB[wave] = b; sC[wave] = c; }
        __syncthreads();
        if (threadIdx.x == 0) {
            float A = sA[0] + sA[1] + sA[2] + sA[3];
            float B = sB[0] + sB[1] + sB[2] + sB[3];
            float C = sC[0] + sC[1] + sC[2] + sC[3];
            float batch = (float)(cells / 169);
            float invb = 1.f / batch;
            float div_obj   = (C > 0.f) ? invb : 1.f;
            float div_noobj = (C < (float)cells) ? invb : 1.f;
            out[0] = A * div_obj + 0.5f * B * div_noobj;
        }
    }
}

extern "C" void kernel_launch(void* const* d_in, const int* in_sizes, int n_in,
                              void* d_out, int out_size, void* d_ws, size_t ws_size,
                              hipStream_t stream) {
    const float* pred = (const float*)d_in[0];
    const float* tgt  = (const float*)d_in[1];
    float* out = (float*)d_out;

    long long cells = (long long)in_sizes[0] / 16;      // 1384448 = 2704 * 512
    int nchunks = (int)(cells / 512);                   // 2704, exact

    int blocks = nchunks;
    // ws layout: [flags: blocks ints][pad to 64B][part: blocks*3 floats]
    size_t flag_bytes = ((size_t)blocks * 4 + 63) & ~(size_t)63;
    size_t need = flag_bytes + (size_t)blocks * 3 * sizeof(float);
    while (need > ws_size && blocks > 1) {
        blocks >>= 1;
        flag_bytes = ((size_t)blocks * 4 + 63) & ~(size_t)63;
        need = flag_bytes + (size_t)blocks * 3 * sizeof(float);
    }

    int* flags = (int*)d_ws;
    float* part = (float*)((char*)d_ws + flag_bytes);

    hipMemsetAsync(flags, 0, (size_t)blocks * 4, stream);   // reset flags each call
    phobia_fused<<<blocks, 256, 0, stream>>>(pred, tgt, flags, part, out, nchunks, cells);
}

// Round 10
// 32.766 us; speedup vs baseline: 5.1691x; 5.1691x over previous
//
#include <hip/hip_runtime.h>
#include <math.h>

// YOLO-style loss: two-kernel streaming reduction (kernel boundary = the only cheap
// cross-XCD fence; per-block agent-scope fences measured 5-7x slower in R5/R6/R9).
// Partial: 4 cells/thread, chunk=1024, grid=1352; partials packed as float4.
// Final: 256 threads, float4 loads (21.6 KB).

#define EPSV 1e-6f

#define CELL_BODY(pA, p4, pB, tA, t4, tB)                                         \
    {                                                                             \
        float m = ((t4) > 0.f) ? 1.f : 0.f;                                       \
        float px = 1.f / (1.f + __expf(-(pA).x));                                 \
        float py = 1.f / (1.f + __expf(-(pA).y));                                 \
        float dx = px - (tA).x;                                                   \
        float dy = py - (tA).y;                                                   \
        float dw = sqrtf(fabsf((pA).z) + EPSV) - sqrtf(fabsf((tA).z) + EPSV);     \
        float dh = sqrtf(fabsf((pA).w) + EPSV) - sqrtf(fabsf((tA).w) + EPSV);     \
        float coord = dx*dx + dy*dy + dw*dw + dh*dh;                              \
        float l1p4 = __logf(1.f + __expf(-fabsf(p4)));                            \
        float logsig_p4 = fminf((p4), 0.f) - l1p4;                                \
        float logsig_m4 = fminf(-(p4), 0.f) - l1p4;                               \
        float bce_obj = -((t4) * logsig_p4 + (1.f - (t4)) * logsig_m4);           \
        float bce_no4 = -logsig_m4;                                               \
        float bce_no9 = fmaxf((pB).x, 0.f) + __logf(1.f + __expf(-fabsf((pB).x)));\
        float t10 = (tB).y, t11 = (tB).z, t12 = (tB).w;                           \
        float p10 = (pB).y, p11 = (pB).z, p12 = (pB).w;                           \
        int tcls = 0; float bt = t10;                                             \
        if (t11 > bt) { bt = t11; tcls = 1; }                                     \
        if (t12 > bt) { tcls = 2; }                                               \
        float lt = (tcls == 0) ? p10 : ((tcls == 1) ? p11 : p12);                 \
        float mx = fmaxf(p10, fmaxf(p11, p12));                                   \
        float lse = mx + __logf(__expf(p10-mx) + __expf(p11-mx) + __expf(p12-mx));\
        float ce = lse - lt;                                                      \
        accA += m * (5.f * coord + bce_obj + ce);                                 \
        accB += (1.f - m) * (bce_no4 + bce_no9);                                  \
        accC += m;                                                                \
    }

typedef float f4u __attribute__((ext_vector_type(4), aligned(4)));

#define LOAD_AND_BODY(cellidx)                                                    \
    {                                                                             \
        long long ii = (cellidx);                                                 \
        const float* pr = pred + ii * 16;                                         \
        const float* tr = tgt  + ii * 13;                                         \
        f4u   pA = *reinterpret_cast<const f4u*>(pr);                             \
        float p4 = pr[4];                                                         \
        f4u   pB = *reinterpret_cast<const f4u*>(pr + 9);                         \
        f4u   tA = *reinterpret_cast<const f4u*>(tr);                             \
        float t4 = tr[4];                                                         \
        f4u   tB = *reinterpret_cast<const f4u*>(tr + 9);                         \
        CELL_BODY(pA, p4, pB, tA, t4, tB);                                        \
    }

__global__ __launch_bounds__(256, 4) void phobia_partial(
    const float* __restrict__ pred, const float* __restrict__ tgt,
    float4* __restrict__ ws, int nchunks)   // chunk = 1024 cells
{
    float accA = 0.f, accB = 0.f, accC = 0.f;

    for (int c = blockIdx.x; c < nchunks; c += gridDim.x) {
        long long base = (long long)c * 1024 + threadIdx.x;
        LOAD_AND_BODY(base);
        LOAD_AND_BODY(base + 256);
        LOAD_AND_BODY(base + 512);
        LOAD_AND_BODY(base + 768);
    }

    // wave64 reduce
    #pragma unroll
    for (int o = 32; o > 0; o >>= 1) {
        accA += __shfl_down(accA, o, 64);
        accB += __shfl_down(accB, o, 64);
        accC += __shfl_down(accC, o, 64);
    }
    __shared__ float sA[4], sB[4], sC[4];
    int wave = threadIdx.x >> 6;
    int lane = threadIdx.x & 63;
    if (lane == 0) { sA[wave] = accA; sB[wave] = accB; sC[wave] = accC; }
    __syncthreads();
    if (threadIdx.x == 0) {
        float4 v;
        v.x = sA[0] + sA[1] + sA[2] + sA[3];
        v.y = sB[0] + sB[1] + sB[2] + sB[3];
        v.z = sC[0] + sC[1] + sC[2] + sC[3];
        v.w = 0.f;
        ws[blockIdx.x] = v;   // single packed store
    }
}

__global__ __launch_bounds__(256) void phobia_final(
    const float4* __restrict__ ws, int nblocks, float* __restrict__ out, long long cells)
{
    float a = 0.f, b = 0.f, c = 0.f;
    for (int i = threadIdx.x; i < nblocks; i += 256) {
        float4 v = ws[i];
        a += v.x; b += v.y; c += v.z;
    }
    #pragma unroll
    for (int o = 32; o > 0; o >>= 1) {
        a += __shfl_down(a, o, 64);
        b += __shfl_down(b, o, 64);
        c += __shfl_down(c, o, 64);
    }
    __shared__ float sA[4], sB[4], sC[4];
    int wave = threadIdx.x >> 6;
    int lane = threadIdx.x & 63;
    if (lane == 0) { sA[wave] = a; sB[wave] = b; sC[wave] = c; }
    __syncthreads();
    if (threadIdx.x == 0) {
        float A = sA[0] + sA[1] + sA[2] + sA[3];
        float B = sB[0] + sB[1] + sB[2] + sB[3];
        float C = sC[0] + sC[1] + sC[2] + sC[3];
        float batch = (float)(cells / 169);
        float invb = 1.f / batch;
        float div_obj   = (C > 0.f) ? invb : 1.f;
        float div_noobj = (C < (float)cells) ? invb : 1.f;
        out[0] = A * div_obj + 0.5f * B * div_noobj;
    }
}

extern "C" void kernel_launch(void* const* d_in, const int* in_sizes, int n_in,
                              void* d_out, int out_size, void* d_ws, size_t ws_size,
                              hipStream_t stream) {
    const float* pred = (const float*)d_in[0];
    const float* tgt  = (const float*)d_in[1];
    float* out = (float*)d_out;
    float4* ws = (float4*)d_ws;

    long long cells = (long long)in_sizes[0] / 16;      // 1384448 = 1352 * 1024
    int nchunks = (int)(cells / 1024);                  // 1352, exact

    int blocks = nchunks;
    size_t need = (size_t)blocks * sizeof(float4);
    while (need > ws_size && blocks > 1) { blocks >>= 1; need = (size_t)blocks * sizeof(float4); }

    phobia_partial<<<blocks, 256, 0, stream>>>(pred, tgt, ws, nchunks);
    phobia_final<<<1, 256, 0, stream>>>(ws, blocks, out, cells);
}